// Round 6
// baseline (418.487 us; speedup 1.0000x reference)
//
#include <hip/hip_runtime.h>
#include <hip/hip_bf16.h>
#include <math.h>

#define NB 16
#define SS 64
#define HH 256
#define FAA 256

using short8 = __attribute__((ext_vector_type(8))) short;
using f32x4  = __attribute__((ext_vector_type(4))) float;

__device__ __forceinline__ unsigned short f2bf(float f) {
  union { float f; unsigned int u; } x; x.f = f;
  unsigned int u = x.u;
  return (unsigned short)((u + 0x7FFFu + ((u >> 16) & 1u)) >> 16);  // RNE
}
__device__ __forceinline__ unsigned int pk2(float a, float b) {
  return (unsigned int)f2bf(a) | ((unsigned int)f2bf(b) << 16);
}

// Pin a 128-bit fragment into explicit physical AGPRs a[LO:HI]. The compiler
// materializes the value there (global_load + v_accvgpr_write) and counts the
// registers; afterwards it considers them dead and never touches AGPRs again
// in this kernel -> the data survives, un-spillable, un-sinkable.
#define PINA(LO, HI, P) \
  asm volatile("" :: "{a[" #LO ":" #HI "]}"(*(const short8*)(P)))

// MFMA reading B from a FIXED physical AGPR range (textual reference: the
// register allocator has no value to track, so no spill/remat is possible).
#define MFMA_PA(ACC, AF, LO, HI) \
  asm volatile("v_mfma_f32_16x16x32_bf16 %0, %1, a[" #LO ":" #HI "], %0" \
               : "+v"(ACC) : "v"(AF))

// ---------------------------------------------------------------------------
// Prolog: fp32 -> bf16 conversions.
// wcat storage row o holds TRUE weight row sr = (o&~31) | ((o&15)<<1) | ((o>>4)&1)
// rows 0..255 = Ur, 256..511 = U.
// ---------------------------------------------------------------------------
__global__ void prolog_cvt(const float* __restrict__ z1w, const float* __restrict__ Ur,
                           const float* __restrict__ U, const float* __restrict__ nmw,
                           const float* __restrict__ pm, const float* __restrict__ qs,
                           unsigned short* __restrict__ z1wbf, unsigned short* __restrict__ wcatbf,
                           unsigned short* __restrict__ nmbf, unsigned short* __restrict__ pmbf,
                           unsigned short* __restrict__ qbf) {
  int idx = blockIdx.x * 256 + threadIdx.x;
  if (idx < 262144) { z1wbf[idx] = f2bf(z1w[idx]); return; }
  idx -= 262144;
  if (idx < 131072) {
    int o = idx >> 8, k = idx & 255;
    int sr = (o & ~31) | ((o & 15) << 1) | ((o >> 4) & 1);  // permuted source row
    wcatbf[idx] = f2bf(sr < 256 ? Ur[sr * 256 + k] : U[(sr - 256) * 256 + k]);
    return;
  }
  idx -= 131072;
  if (idx < 196608) { nmbf[idx] = f2bf(nmw[idx]); return; }
  idx -= 196608;
  if (idx < 262144) { pmbf[idx] = f2bf(pm[idx]); return; }
  idx -= 262144;
  if (idx < 262144) { qbf[idx] = f2bf(qs[idx]); return; }
}

// ---------------------------------------------------------------------------
// Phase B: FWr[b,h] = facts[b]·Wr[h] + Wr_b[h] + Ur_b[h];  FW[b,h] = facts[b]·W[h] + W_b[h]
// ---------------------------------------------------------------------------
__global__ __launch_bounds__(256) void fact_proj(
    const float* __restrict__ facts, const float* __restrict__ Wr, const float* __restrict__ Wrb,
    const float* __restrict__ Urb, const float* __restrict__ Ww, const float* __restrict__ Wb,
    float* __restrict__ FWr, float* __restrict__ FW) {
  __shared__ float fl[4][HH];
  const int b0 = blockIdx.x * 4;
  const int tid = threadIdx.x;
#pragma unroll
  for (int r = 0; r < 4; ++r) fl[r][tid] = facts[(b0 + r) * HH + tid];
  __syncthreads();
  float ar[4] = {0.f, 0.f, 0.f, 0.f}, aw[4] = {0.f, 0.f, 0.f, 0.f};
  const float4* wr = (const float4*)(Wr + tid * HH);
  const float4* ww = (const float4*)(Ww + tid * HH);
  for (int d4 = 0; d4 < 64; ++d4) {
    float4 a = wr[d4], b = ww[d4];
#pragma unroll
    for (int r = 0; r < 4; ++r) {
      float4 f = *(const float4*)&fl[r][d4 * 4];  // LDS broadcast
      ar[r] += a.x * f.x + a.y * f.y + a.z * f.z + a.w * f.w;
      aw[r] += b.x * f.x + b.y * f.y + b.z * f.z + b.w * f.w;
    }
  }
  const float br = Wrb[tid] + Urb[tid], bw = Wb[tid];
#pragma unroll
  for (int r = 0; r < 4; ++r) {
    FWr[(b0 + r) * HH + tid] = ar[r] + br;
    FW[(b0 + r) * HH + tid] = aw[r] + bw;
  }
}

// ---------------------------------------------------------------------------
// Phase A: gate GEMM. (unchanged)
// ---------------------------------------------------------------------------
__global__ __launch_bounds__(512, 2) void gate_gemm(
    const float* __restrict__ facts, const float* __restrict__ prevM,
    const float* __restrict__ questions, const unsigned short* __restrict__ z1wbf,
    const float* __restrict__ z1b, const float* __restrict__ z2w,
    const float* __restrict__ z2b, float* __restrict__ G) {
  __shared__ unsigned short A[128][136];
  __shared__ float Gpart[128][4];
  const int bi = blockIdx.x;
  const int n = bi >> 5, i0 = (bi & 31) * 2;
  const int tid = threadIdx.x;
  const int w = tid >> 6, l = tid & 63;
  const int rg = w >> 2, cg = w & 3;
  const int l15 = l & 15, q = l >> 4;
  const int hh2 = (tid & 15) * 2, jb = tid >> 4;

  const float* fn = facts + n * SS * HH;
  const float* qn = questions + (n * SS + i0) * HH;
  const float* mn = prevM + (n * SS + i0) * HH;

  const f32x4 zero4 = {0.f, 0.f, 0.f, 0.f};
  f32x4 acc[4][4];
#pragma unroll
  for (int a = 0; a < 4; ++a)
#pragma unroll
    for (int b = 0; b < 4; ++b) acc[a][b] = zero4;

  float2 fv0, fv1, qv0, qv1, mv0, mv1;
  auto prefetch = [&](int hc) {
    const int h = hc * 32 + hh2;
    fv0 = *(const float2*)(fn + jb * HH + h);
    fv1 = *(const float2*)(fn + (jb + 32) * HH + h);
    qv0 = *(const float2*)(qn + h);
    qv1 = *(const float2*)(qn + HH + h);
    mv0 = *(const float2*)(mn + h);
    mv1 = *(const float2*)(mn + HH + h);
  };
  prefetch(0);

  for (int hc = 0; hc < 8; ++hc) {
    {
      float2 fl2[2] = {fv0, fv1}, ql2[2] = {qv0, qv1}, ml2[2] = {mv0, mv1};
#pragma unroll
      for (int pl = 0; pl < 2; ++pl) {
        const int j = jb + pl * 32;
#pragma unroll
        for (int il = 0; il < 2; ++il) {
          const int row = il * 64 + j;
          const float fx = fl2[pl].x, fy = fl2[pl].y;
          const float qx = ql2[il].x, qy = ql2[il].y;
          const float mx = ml2[il].x, my = ml2[il].y;
          *(unsigned int*)&A[row][0 * 32 + hh2] = pk2(fx * qx, fy * qy);
          *(unsigned int*)&A[row][1 * 32 + hh2] = pk2(fx * mx, fy * my);
          *(unsigned int*)&A[row][2 * 32 + hh2] = pk2(fabsf(fx - qx), fabsf(fy - qy));
          *(unsigned int*)&A[row][3 * 32 + hh2] = pk2(fabsf(fx - mx), fabsf(fy - my));
        }
      }
    }
    if (hc < 7) prefetch(hc + 1);
    __syncthreads();

    const unsigned short* bb = z1wbf + (cg * 64 + l15) * 1024 + hc * 32 + q * 8;
#pragma unroll
    for (int s = 0; s < 4; ++s) {
      short8 Bf[4];
#pragma unroll
      for (int nf = 0; nf < 4; ++nf)
        Bf[nf] = *(const short8*)(bb + (nf * 16) * 1024 + s * 256);
      short8 Af[4];
#pragma unroll
      for (int mf = 0; mf < 4; ++mf)
        Af[mf] = *(const short8*)&A[rg * 64 + mf * 16 + l15][s * 32 + q * 8];
#pragma unroll
      for (int mf = 0; mf < 4; ++mf)
#pragma unroll
        for (int nf = 0; nf < 4; ++nf)
          acc[mf][nf] = __builtin_amdgcn_mfma_f32_16x16x32_bf16(Af[mf], Bf[nf], acc[mf][nf], 0, 0, 0);
    }
    __syncthreads();
  }

  float psum[4][4];
#pragma unroll
  for (int mf = 0; mf < 4; ++mf)
#pragma unroll
    for (int v = 0; v < 4; ++v) psum[mf][v] = 0.f;

#pragma unroll
  for (int nf = 0; nf < 4; ++nf) {
    const int k = cg * 64 + nf * 16 + l15;
    const float zb = z1b[k], zw = z2w[k];
#pragma unroll
    for (int mf = 0; mf < 4; ++mf)
#pragma unroll
      for (int v = 0; v < 4; ++v) {
        const float x = acc[mf][nf][v] + zb;
        const float e = __expf(2.f * x);
        const float t = 1.f - 2.f / (e + 1.f);
        psum[mf][v] += zw * t;
      }
  }
#pragma unroll
  for (int d = 1; d < 16; d <<= 1)
#pragma unroll
    for (int mf = 0; mf < 4; ++mf)
#pragma unroll
      for (int v = 0; v < 4; ++v) psum[mf][v] += __shfl_xor(psum[mf][v], d, 64);
  if (l15 == 0) {
#pragma unroll
    for (int mf = 0; mf < 4; ++mf)
#pragma unroll
      for (int v = 0; v < 4; ++v)
        Gpart[rg * 64 + mf * 16 + q * 4 + v][cg] = psum[mf][v];
  }
  __syncthreads();
  if (tid < 128) {
    const float g = Gpart[tid][0] + Gpart[tid][1] + Gpart[tid][2] + Gpart[tid][3] + z2b[0];
    const int i = i0 + (tid >> 6), j = tid & 63;
    G[(n * SS + i) * SS + j] = g;
  }
}

// ---------------------------------------------------------------------------
// Phase A2: masked softmax over j. One wave per (n,i); lane = j.
// ---------------------------------------------------------------------------
__global__ void softmax_attn(const float* __restrict__ G, const int* __restrict__ doc_len,
                             float* __restrict__ attn) {
  const int gid = blockIdx.x * 256 + threadIdx.x;
  const int wid = gid >> 6, l = gid & 63;
  const int n = wid >> 6, i = wid & 63;
  const int dl = doc_len[n];
  const float g = G[(n * SS + i) * SS + l];
  const float x = (l < dl && g != 0.0f) ? g : -INFINITY;
  float mx = x;
#pragma unroll
  for (int d = 1; d < 64; d <<= 1) mx = fmaxf(mx, __shfl_xor(mx, d, 64));
  const float e = (x == -INFINITY) ? 0.f : __expf(x - mx);
  float s = e;
#pragma unroll
  for (int d = 1; d < 64; d <<= 1) s += __shfl_xor(s, d, 64);
  attn[(n * SS + i) * SS + l] = e / s;
}

// ---------------------------------------------------------------------------
// Phase C: GRU scan, 1 barrier/step. R6: B-fragments live in EXPLICIT physical
// AGPRs a0-a127. PINA materializes them once (counted in resource usage);
// the in-loop MFMAs reference a[LO:HI] textually, so the register allocator
// holds NO value to spill/remat — the R2-R5 failure mode (legal scratch spill
// + per-step reload: ~4100 cyc/step of L1/VMEM traffic) is structurally
// impossible. Kernel has no other AGPR use (no builtin MFMA here) and ~100
// arch VGPRs, so the compiler won't touch a0-a127 on its own.
// Layout: Br0->a[0:31], Br1->a[32:63], Bu0->a[64:95], Bu1->a[96:127].
// ---------------------------------------------------------------------------
__global__ __launch_bounds__(512, 2) void gru_scan(
    const unsigned short* __restrict__ wcat, const float* __restrict__ FWr,
    const float* __restrict__ FW, const float* __restrict__ Ub,
    const float* __restrict__ attn, unsigned short* __restrict__ Cout) {
  __shared__ unsigned short Cbf[2][16 * 266];  // 133-word stride: conflict-free b128 reads
  __shared__ float attn_s[16 * 65];

  const int bi = blockIdx.x, n = bi >> 2, i0 = (bi & 3) * 16;
  const int tid = threadIdx.x, w = tid >> 6, l = tid & 63;
  const int l15 = l & 15, q = l >> 4;
  const int h0 = w * 32 + 2 * l15;  // true col of tile nf=0; nf=1 is h0+1

  // ---- pin B-fragments into physical AGPRs (once) ----
  {
    const unsigned short* b0 = wcat + (w * 32 + l15) * 256 + q * 8;
    PINA(0, 3, b0 + 0);       PINA(4, 7, b0 + 32);      PINA(8, 11, b0 + 64);
    PINA(12, 15, b0 + 96);    PINA(16, 19, b0 + 128);   PINA(20, 23, b0 + 160);
    PINA(24, 27, b0 + 192);   PINA(28, 31, b0 + 224);
    PINA(32, 35, b0 + 4096);  PINA(36, 39, b0 + 4128);  PINA(40, 43, b0 + 4160);
    PINA(44, 47, b0 + 4192);  PINA(48, 51, b0 + 4224);  PINA(52, 55, b0 + 4256);
    PINA(56, 59, b0 + 4288);  PINA(60, 63, b0 + 4320);
    PINA(64, 67, b0 + 65536); PINA(68, 71, b0 + 65568); PINA(72, 75, b0 + 65600);
    PINA(76, 79, b0 + 65632); PINA(80, 83, b0 + 65664); PINA(84, 87, b0 + 65696);
    PINA(88, 91, b0 + 65728); PINA(92, 95, b0 + 65760);
    PINA(96, 99, b0 + 69632); PINA(100, 103, b0 + 69664); PINA(104, 107, b0 + 69696);
    PINA(108, 111, b0 + 69728); PINA(112, 115, b0 + 69760); PINA(116, 119, b0 + 69792);
    PINA(120, 123, b0 + 69824); PINA(124, 127, b0 + 69856);
    // accvgpr_write -> mfma-read hazard guard (compiler can't see the reads)
    asm volatile("s_nop 7\n\ts_nop 7");
  }

  const float2 ub2 = *(const float2*)(Ub + h0);

  for (int e = tid; e < 16 * 64; e += 512)
    attn_s[(e >> 6) * 65 + (e & 63)] = attn[(n * SS + i0 + (e >> 6)) * SS + (e & 63)];
  for (int e = tid; e < (16 * 266) / 2; e += 512) ((unsigned int*)Cbf[0])[e] = 0u;
  __syncthreads();

  float Cf0[4] = {0.f, 0.f, 0.f, 0.f}, Cf1[4] = {0.f, 0.f, 0.f, 0.f};

  const float* fwr_g = FWr + (n * SS) * HH + h0;
  const float* fw_g  = FW + (n * SS) * HH + h0;
  float2 fwr2 = *(const float2*)(fwr_g);
  float2 fw2  = *(const float2*)(fw_g);

  for (int t = 0; t < 64; ++t) {
    // prefetch next step's per-col scalars early (drained at the barrier)
    const int tn = (t + 1) & 63;
    const float2 fwr2n = *(const float2*)(fwr_g + tn * HH);
    const float2 fw2n  = *(const float2*)(fw_g + tn * HH);

    const unsigned short* cb = Cbf[t & 1] + l15 * 266 + q * 8;
    short8 Af[8];
#pragma unroll
    for (int kt = 0; kt < 8; ++kt) Af[kt] = *(const short8*)(cb + kt * 32);

    f32x4 ar0 = {0.f, 0.f, 0.f, 0.f}, ar1 = ar0, au0 = ar0, au1 = ar0;
    // >=2-cycle gap between acc zero-init (VALU writes) and first MFMA read
    asm volatile("s_nop 1" : "+v"(ar0), "+v"(ar1), "+v"(au0), "+v"(au1));

    MFMA_PA(ar0, Af[0], 0, 3);    MFMA_PA(ar1, Af[0], 32, 35);
    MFMA_PA(au0, Af[0], 64, 67);  MFMA_PA(au1, Af[0], 96, 99);
    MFMA_PA(ar0, Af[1], 4, 7);    MFMA_PA(ar1, Af[1], 36, 39);
    MFMA_PA(au0, Af[1], 68, 71);  MFMA_PA(au1, Af[1], 100, 103);
    MFMA_PA(ar0, Af[2], 8, 11);   MFMA_PA(ar1, Af[2], 40, 43);
    MFMA_PA(au0, Af[2], 72, 75);  MFMA_PA(au1, Af[2], 104, 107);
    MFMA_PA(ar0, Af[3], 12, 15);  MFMA_PA(ar1, Af[3], 44, 47);
    MFMA_PA(au0, Af[3], 76, 79);  MFMA_PA(au1, Af[3], 108, 111);
    MFMA_PA(ar0, Af[4], 16, 19);  MFMA_PA(ar1, Af[4], 48, 51);
    MFMA_PA(au0, Af[4], 80, 83);  MFMA_PA(au1, Af[4], 112, 115);
    MFMA_PA(ar0, Af[5], 20, 23);  MFMA_PA(ar1, Af[5], 52, 55);
    MFMA_PA(au0, Af[5], 84, 87);  MFMA_PA(au1, Af[5], 116, 119);
    MFMA_PA(ar0, Af[6], 24, 27);  MFMA_PA(ar1, Af[6], 56, 59);
    MFMA_PA(au0, Af[6], 88, 91);  MFMA_PA(au1, Af[6], 120, 123);
    MFMA_PA(ar0, Af[7], 28, 31);  MFMA_PA(ar1, Af[7], 60, 63);
    MFMA_PA(au0, Af[7], 92, 95);  MFMA_PA(au1, Af[7], 124, 127);

    // MFMA dest -> VALU read hazard guard (ordered via operand dataflow)
    asm volatile("s_nop 7\n\ts_nop 7" : "+v"(ar0), "+v"(ar1), "+v"(au0), "+v"(au1));

    unsigned short* cw = Cbf[(t + 1) & 1];
#pragma unroll
    for (int v = 0; v < 4; ++v) {
      const int row = q * 4 + v;
      const float g = attn_s[row * 65 + t];
      float cn0, cn1;
      {
        const float r  = 1.f / (1.f + __expf(-(fwr2.x + ar0[v])));
        const float x  = fw2.x + r * (au0[v] + ub2.x);
        const float eh = __expf(2.f * x);
        const float ht = 1.f - 2.f / (eh + 1.f);
        cn0 = g * ht + (1.f - g) * Cf0[v];
        Cf0[v] = cn0;
      }
      {
        const float r  = 1.f / (1.f + __expf(-(fwr2.y + ar1[v])));
        const float x  = fw2.y + r * (au1[v] + ub2.y);
        const float eh = __expf(2.f * x);
        const float ht = 1.f - 2.f / (eh + 1.f);
        cn1 = g * ht + (1.f - g) * Cf1[v];
        Cf1[v] = cn1;
      }
      *(unsigned int*)&cw[row * 266 + h0] = pk2(cn0, cn1);
    }
    fwr2 = fwr2n;
    fw2 = fw2n;
    __syncthreads();
  }

  // final C (bf16) for phase D, true col order
#pragma unroll
  for (int v = 0; v < 4; ++v) {
    const int row = i0 + q * 4 + v;
    *(unsigned int*)&Cout[(n * SS + row) * HH + h0] = pk2(Cf0[v], Cf1[v]);
  }
}

// ---------------------------------------------------------------------------
// Phase D: next_mem = relu([prevM | C | questions] @ nm_w^T + nm_b)
// ---------------------------------------------------------------------------
__global__ __launch_bounds__(256) void next_mem_gemm(
    const unsigned short* __restrict__ pmbf, const unsigned short* __restrict__ cbf,
    const unsigned short* __restrict__ qbf, const unsigned short* __restrict__ nmbf,
    const float* __restrict__ nmb, float* __restrict__ out) {
  __shared__ unsigned short A[64][40];
  const int bi = blockIdx.x;
  const int rb = bi >> 2, cb = bi & 3;
  const int r0 = rb * 64, c0 = cb * 64;
  const int tid = threadIdx.x, w = tid >> 6, l = tid & 63;
  const int l15 = l & 15, q = l >> 4;

  f32x4 acc[4];
  const f32x4 z4 = {0.f, 0.f, 0.f, 0.f};
#pragma unroll
  for (int nf = 0; nf < 4; ++nf) acc[nf] = z4;

  for (int kt = 0; kt < 24; ++kt) {
    const int kg = kt * 32;
    const unsigned short* src =
        kg < 256 ? (pmbf + kg) : (kg < 512 ? (cbf + kg - 256) : (qbf + kg - 512));
    const int kk = (tid & 15) * 2;
#pragma unroll
    for (int ps = 0; ps < 4; ++ps) {
      const int row = ps * 16 + (tid >> 4);
      *(unsigned int*)&A[row][kk] = *(const unsigned int*)(src + (r0 + row) * HH + kk);
    }
    __syncthreads();
    short8 Bfr[4];
#pragma unroll
    for (int nf = 0; nf < 4; ++nf)
      Bfr[nf] = *(const short8*)(nmbf + (c0 + nf * 16 + l15) * 768 + kg + q * 8);
    const short8 Af = *(const short8*)&A[w * 16 + l15][q * 8];
#pragma unroll
    for (int nf = 0; nf < 4; ++nf)
      acc[nf] = __builtin_amdgcn_mfma_f32_16x16x32_bf16(Af, Bfr[nf], acc[nf], 0, 0, 0);
    __syncthreads();
  }
#pragma unroll
  for (int nf = 0; nf < 4; ++nf) {
    const int col = c0 + nf * 16 + l15;
    const float bv = nmb[col];
#pragma unroll
    for (int v = 0; v < 4; ++v) {
      const int grow = r0 + w * 16 + q * 4 + v;
      out[grow * HH + col] = fmaxf(acc[nf][v] + bv, 0.f);
    }
  }
}

// ---------------------------------------------------------------------------
extern "C" void kernel_launch(void* const* d_in, const int* in_sizes, int n_in,
                              void* d_out, int out_size, void* d_ws, size_t ws_size,
                              hipStream_t stream) {
  const float* facts     = (const float*)d_in[0];
  const float* prevM     = (const float*)d_in[1];
  const float* questions = (const float*)d_in[2];
  const int*   doc_len   = (const int*)d_in[3];
  const float* z1w = (const float*)d_in[4];
  const float* z1b = (const float*)d_in[5];
  const float* z2w = (const float*)d_in[6];
  const float* z2b = (const float*)d_in[7];
  const float* Wrw = (const float*)d_in[8];
  const float* Wrb = (const float*)d_in[9];
  const float* Urw = (const float*)d_in[10];
  const float* Urb = (const float*)d_in[11];
  const float* Ww  = (const float*)d_in[12];
  const float* Wb  = (const float*)d_in[13];
  const float* Uw  = (const float*)d_in[14];
  const float* Ub  = (const float*)d_in[15];
  const float* nmw = (const float*)d_in[16];
  const float* nmb = (const float*)d_in[17];

  char* ws = (char*)d_ws;
  unsigned short* z1wbf  = (unsigned short*)(ws + 0);        // 512 KB
  unsigned short* wcatbf = (unsigned short*)(ws + 524288);   // 256 KB
  unsigned short* nmbf   = (unsigned short*)(ws + 786432);   // 384 KB
  unsigned short* pmbf   = (unsigned short*)(ws + 1179648);  // 512 KB
  unsigned short* qbf    = (unsigned short*)(ws + 1703936);  // 512 KB
  float* G   = (float*)(ws + 2228224);                       // 256 KB
  float* FWr = (float*)(ws + 2490368);                       // 1 MB
  float* FW  = (float*)(ws + 3538944);                       // 1 MB
  unsigned short* cbf = (unsigned short*)(ws + 4587520);     // 512 KB

  float* out  = (float*)d_out;
  float* attn = out + NB * SS * HH;

  prolog_cvt<<<4352, 256, 0, stream>>>(z1w, Urw, Uw, nmw, prevM, questions,
                                       z1wbf, wcatbf, nmbf, pmbf, qbf);
  fact_proj<<<256, 256, 0, stream>>>(facts, Wrw, Wrb, Urb, Ww, Wb, FWr, FW);
  gate_gemm<<<512, 512, 0, stream>>>(facts, prevM, questions, z1wbf, z1b, z2w, z2b, G);
  softmax_attn<<<256, 256, 0, stream>>>(G, doc_len, attn);
  gru_scan<<<64, 512, 0, stream>>>(wcatbf, FWr, FW, Ub, attn, cbf);
  next_mem_gemm<<<64, 256, 0, stream>>>(pmbf, cbf, qbf, nmbf, nmb, out);
}